// Round 5
// baseline (985.089 us; speedup 1.0000x reference)
//
#include <hip/hip_runtime.h>
#include <math.h>

// Problem dims (AttentionRNN): B=128, T=64, H=256, V=128
#define BB 128
#define TT 64
#define HH 256
#define G3 768   // 3*H
#define VV 128

typedef _Float16 half8 __attribute__((ext_vector_type(8)));
typedef float f32x4 __attribute__((ext_vector_type(4)));

// ---------------------------------------------------------------------------
// Pack w_hh [768][256] f32 -> f16 MFMA B-fragments, in the exact per-lane
// order gru_mfma consumes: [wave 8][tile 6][ktile 8][lane 64][elem 8].
// Fragment def (v_mfma_f32_16x16x32_f16 B): col = lane&15, k = (lane>>4)*8+e.
// Tile tau: gate g = tau/2, sub s = tau&1 -> ncol = g*256 + wave*32 + s*16.
// ---------------------------------------------------------------------------
__global__ __launch_bounds__(256) void pack_whh_f16(const float* __restrict__ w,
                                                    _Float16* __restrict__ out) {
    int d = blockIdx.x * 256 + threadIdx.x;   // 196608 total
    int e   = d & 7;
    int l   = (d >> 3) & 63;
    int kap = (d >> 9) & 7;
    int wt  = d >> 12;                        // wave*6 + tau
    int wv  = wt / 6, tau = wt % 6;
    int ncol = (tau >> 1) * 256 + wv * 32 + (tau & 1) * 16 + (l & 15);
    int k    = kap * 32 + (l >> 4) * 8 + e;
    out[d] = (_Float16)w[ncol * HH + k];
}

// Folded bias: out[j] = b_ih[j] + (j<512 ? b_hh[j] : 0).  (r,z parts of b_hh
// ride along in xp; the n part stays separate since it's scaled by r.)
__global__ __launch_bounds__(256) void prep_bias(const float* __restrict__ b_ih,
                                                 const float* __restrict__ b_hh,
                                                 float* __restrict__ outb) {
    int j = blockIdx.x * 256 + threadIdx.x;   // 768
    outb[j] = b_ih[j] + (j < 2 * HH ? b_hh[j] : 0.f);
}

// ---------------------------------------------------------------------------
// Generic f32 GEMM: C[M,N] = A[M,K1+K2] @ B[N,K1+K2]^T + bias.
// permmode 0: normal row-major C [M][ldc], float4 stores.
// permmode 1 (N must be 768): xp layout, C[r][c*4+g] width 1024 (j = g*256+c).
// permmode 2: same + t-major row permute r=(b*64+t) -> orow = t*128+b.
// ---------------------------------------------------------------------------
__global__ __launch_bounds__(256) void gemm_bt(
    const float* __restrict__ A1, int lda1, int K1,
    const float* __restrict__ A2, int lda2, int K2,
    const float* __restrict__ Bw, int ldb,
    const float* __restrict__ bias,
    float* __restrict__ C, int ldc, int M, int N, int permmode)
{
    __shared__ alignas(16) float As[16][68];
    __shared__ alignas(16) float Bs[16][68];
    const int tid = threadIdx.x;
    const int lc = tid & 15, lr = tid >> 4;
    const int ty = tid >> 4, tx = tid & 15;
    const int row0 = blockIdx.y * 64, col0 = blockIdx.x * 64;
    float acc[4][4] = {};
    const int KT = K1 + K2;

    for (int k0 = 0; k0 < KT; k0 += 16) {
        const float* Ap; int lda, kk0;
        if (k0 < K1) { Ap = A1; lda = lda1; kk0 = k0; }
        else         { Ap = A2; lda = lda2; kk0 = k0 - K1; }
#pragma unroll
        for (int r = 0; r < 4; ++r) {
            As[lc][lr + 16 * r] = Ap[(row0 + lr + 16 * r) * lda + kk0 + lc];
            Bs[lc][lr + 16 * r] = Bw[(col0 + lr + 16 * r) * ldb + k0 + lc];
        }
        __syncthreads();
#pragma unroll
        for (int kk = 0; kk < 16; ++kk) {
            const float4 a4 = *(const float4*)&As[kk][ty * 4];
            const float4 b4 = *(const float4*)&Bs[kk][tx * 4];
            const float av[4] = {a4.x, a4.y, a4.z, a4.w};
            const float bv[4] = {b4.x, b4.y, b4.z, b4.w};
#pragma unroll
            for (int i = 0; i < 4; ++i)
#pragma unroll
                for (int j = 0; j < 4; ++j)
                    acc[i][j] += av[i] * bv[j];
        }
        __syncthreads();
    }

    float bv[4];
#pragma unroll
    for (int j = 0; j < 4; ++j)
        bv[j] = bias ? bias[col0 + tx * 4 + j] : 0.f;
#pragma unroll
    for (int i = 0; i < 4; ++i) {
        const int r = row0 + ty * 4 + i;
        if (permmode == 0) {
            float4 o;
            o.x = acc[i][0] + bv[0];
            o.y = acc[i][1] + bv[1];
            o.z = acc[i][2] + bv[2];
            o.w = acc[i][3] + bv[3];
            *(float4*)&C[r * ldc + col0 + tx * 4] = o;
        } else {
            const int orow = (permmode == 2) ? ((r & 63) * BB + (r >> 6)) : r;
#pragma unroll
            for (int jj = 0; jj < 4; ++jj) {
                const int j = col0 + tx * 4 + jj;
                const int g = j >> 8, c = j & 255;
                C[orow * 1024 + c * 4 + g] = acc[i][jj] + bv[jj];
            }
        }
    }
}

// ---------------------------------------------------------------------------
// MFMA GRU layer, register-resident weights + prefetched xp.
// 8 blocks x 16 batch rows, 512 threads (8 waves), 1 block/CU.
// Per step: issue xp(t+1) float4 loads -> 8 ds_read A-frags -> 48 MFMA
// (2 waves/SIMD x 19.4cy = ~1862cy, the floor) -> gates -> write hbuf[nxt].
// hbuf double-buffered: ONE barrier per step.
// xsrc layout: [row][1024] with (xr,xz,xn,pad) at c*4 (see gemm_bt perm).
// mode 0: row = token id (P0).  mode 1: row = t*128 + batch (xp1, t-major).
// ---------------------------------------------------------------------------
__global__ __launch_bounds__(512, 2) void gru_mfma(
    const _Float16* __restrict__ wp,  // packed fragments (see pack_whh_f16)
    const float* __restrict__ b_hh,   // [768]; only [512:768) used here
    const float* __restrict__ xsrc,   // padded xp, width 1024
    const int*   __restrict__ xidx,   // token ids (mode0)
    float* __restrict__ out_seq,      // [B*T][256]
    float* __restrict__ hlast,        // [B][256] (mode1 only)
    int mode)
{
    __shared__ alignas(16) _Float16 hbuf[2][16][264];   // double buffer, +8 pad
    __shared__ int tok[16][TT];                          // mode0 token ids
    const int tid = threadIdx.x;
    const int wv = tid >> 6, l = tid & 63;
    const int l15 = l & 15, lhi = l >> 4;
    const int r0 = blockIdx.x * 16;

    for (int i = tid; i < 16 * 264; i += 512) ((_Float16*)hbuf[0])[i] = (_Float16)0.f;
    if (mode == 0) {
        ((int*)tok)[tid]       = xidx[r0 * TT + tid];
        ((int*)tok)[tid + 512] = xidx[r0 * TT + tid + 512];
    }

    // ---- load all 48 weight fragments into registers (once) ----
    half8 W[48];
    const half8* wp8 = (const half8*)wp;
    const int fb = wv * 48 * 64;
#pragma unroll
    for (int f = 0; f < 48; ++f) W[f] = wp8[fb + f * 64 + l];

    const int colbase = wv * 32 + l15;
    const float bhn0 = b_hh[2 * HH + colbase];
    const float bhn1 = b_hh[2 * HH + colbase + 16];
    float hold[2][4] = {};
    __syncthreads();   // hbuf[0] zeros + tok visible

    float4 xqA[2][4], xqB[2][4];
    // prefetch xp(0)
#pragma unroll
    for (int s = 0; s < 2; ++s) {
        const int c = colbase + 16 * s;
#pragma unroll
        for (int reg = 0; reg < 4; ++reg) {
            const int rr = lhi * 4 + reg;
            const long row = (mode == 0) ? (long)tok[rr][0] : (long)(r0 + rr);
            xqA[s][reg] = *(const float4*)&xsrc[row * 1024 + c * 4];
        }
    }

    int cur = 0;
    for (int t = 0; t < TT; ++t) {
        // issue xp(t+1) loads first: latency hides under the MFMA phase
        if (t + 1 < TT) {
#pragma unroll
            for (int s = 0; s < 2; ++s) {
                const int c = colbase + 16 * s;
#pragma unroll
                for (int reg = 0; reg < 4; ++reg) {
                    const int rr = lhi * 4 + reg;
                    const long row = (mode == 0)
                        ? (long)tok[rr][t + 1]
                        : (long)(t + 1) * BB + (r0 + rr);
                    xqB[s][reg] = *(const float4*)&xsrc[row * 1024 + c * 4];
                }
            }
        }

        f32x4 acc[6];
#pragma unroll
        for (int tau = 0; tau < 6; ++tau) acc[tau] = (f32x4)0.f;

#pragma unroll
        for (int kap = 0; kap < 8; ++kap) {
            const half8 a = *(const half8*)&hbuf[cur][l15][kap * 32 + lhi * 8];
#pragma unroll
            for (int tau = 0; tau < 6; ++tau)
                acc[tau] = __builtin_amdgcn_mfma_f32_16x16x32_f16(
                    a, W[tau * 8 + kap], acc[tau], 0, 0, 0);
        }

        // gates: C-layout col = l&15, row = (l>>4)*4 + reg; write to hbuf[cur^1]
#pragma unroll
        for (int s = 0; s < 2; ++s) {
            const int col = colbase + s * 16;
            const float bhn = s ? bhn1 : bhn0;
#pragma unroll
            for (int reg = 0; reg < 4; ++reg) {
                const int row = lhi * 4 + reg;
                const float pr = acc[0 + s][reg] + xqA[s][reg].x;
                const float pz = acc[2 + s][reg] + xqA[s][reg].y;
                const float hn = acc[4 + s][reg] + bhn;
                const float rg = 1.f / (1.f + __expf(-pr));
                const float zg = 1.f / (1.f + __expf(-pz));
                const float npre = xqA[s][reg].z + rg * hn;
                const float e2 = __expf(2.f * npre);
                const float ng = (e2 - 1.f) / (e2 + 1.f);
                const float hnew = (1.f - zg) * ng + zg * hold[s][reg];
                hold[s][reg] = hnew;
                hbuf[cur ^ 1][row][col] = (_Float16)hnew;
                const int brow = r0 + row;
                out_seq[(brow * TT + t) * HH + col] = hnew;
                if (mode == 1 && t == TT - 1) hlast[brow * HH + col] = hnew;
            }
        }

        // rotate prefetch regs (compiler inserts the vmcnt wait here)
#pragma unroll
        for (int s = 0; s < 2; ++s)
#pragma unroll
            for (int reg = 0; reg < 4; ++reg)
                xqA[s][reg] = xqB[s][reg];

        cur ^= 1;
        __syncthreads();   // one barrier per step (double-buffered hbuf)
    }
}

// ---------------------------------------------------------------------------
// Bahdanau attention, one block per (b,t): energy -> softmax(k) -> ctx.
// WU holds [Wa_e | Ua_h] per row (stride 512).
// ---------------------------------------------------------------------------
__device__ __forceinline__ float tanh_fast(float x) {
    const float e = __expf(2.f * x);
    return (e - 1.f) / (e + 1.f);
}

__global__ __launch_bounds__(256) void attn_kernel(
    const float* __restrict__ WU,    // [B*T][512]: cols 0..255 Wa_e, 256..511 Ua_h
    const float* __restrict__ enc,   // [B*T][256]
    const float* __restrict__ v_a,   // [256]
    float* __restrict__ ctx)         // [B*T][256]
{
    __shared__ float q[HH], va[HH], sm[TT];
    const int tid = threadIdx.x;
    const int t = blockIdx.x, b = blockIdx.y;

    q[tid]  = WU[(b * TT + t) * 512 + 256 + tid];
    va[tid] = v_a[tid];
    __syncthreads();

    const int w = tid >> 6, lane = tid & 63;
#pragma unroll 4
    for (int i = 0; i < 16; ++i) {
        const int k = w * 16 + i;
        const float* we = WU + (b * TT + k) * 512;
        float s = 0.f;
#pragma unroll
        for (int c = 0; c < 4; ++c) {
            const int h = lane + 64 * c;
            s += va[h] * tanh_fast(we[h] + q[h]);
        }
#pragma unroll
        for (int off = 32; off > 0; off >>= 1) s += __shfl_xor(s, off);
        if (lane == 0) sm[k] = s;
    }
    __syncthreads();

    if (tid < TT) {
        const float e = sm[tid];
        float mx = e;
#pragma unroll
        for (int off = 32; off > 0; off >>= 1) mx = fmaxf(mx, __shfl_xor(mx, off));
        const float p = __expf(e - mx);
        float sum = p;
#pragma unroll
        for (int off = 32; off > 0; off >>= 1) sum += __shfl_xor(sum, off);
        sm[tid] = p / sum;
    }
    __syncthreads();

    float c = 0.f;
    for (int k = 0; k < TT; ++k)
        c += sm[k] * enc[(b * TT + k) * HH + tid];
    ctx[(b * TT + t) * HH + tid] = c;
}

// ---------------------------------------------------------------------------
extern "C" void kernel_launch(void* const* d_in, const int* in_sizes, int n_in,
                              void* d_out, int out_size, void* d_ws, size_t ws_size,
                              hipStream_t stream) {
    const int*   x     = (const int*)  d_in[0];
    const float* embed = (const float*)d_in[1];
    const float* w_ih0 = (const float*)d_in[2];
    const float* w_hh0 = (const float*)d_in[3];
    const float* b_ih0 = (const float*)d_in[4];
    const float* b_hh0 = (const float*)d_in[5];
    const float* w_ih1 = (const float*)d_in[6];
    const float* w_hh1 = (const float*)d_in[7];
    const float* b_ih1 = (const float*)d_in[8];
    const float* b_hh1 = (const float*)d_in[9];
    const float* W_a   = (const float*)d_in[10];
    const float* U_a   = (const float*)d_in[11];
    const float* v_a   = (const float*)d_in[12];
    const float* fc_W  = (const float*)d_in[13];
    const float* fc_b  = (const float*)d_in[14];
    float* out = (float*)d_out;

    // workspace layout (float words); WU/ctx alias dead xp1
    float* ws = (float*)d_ws;
    _Float16* wT0 = (_Float16*)ws;        // 196608 f16 = 98304 f
    _Float16* wT1 = wT0 + 196608;         // 196608 f16
    float* bias0 = ws    + 196608;        // 768
    float* bias1 = bias0 + 768;           // 768
    float* P0    = bias1 + 768;           // 131072  [128][1024] padded xp
    float* h1    = P0    + 131072;        // 2097152
    float* enc   = h1    + 2097152;       // 2097152
    float* WU_B  = enc   + 2097152;       // 131072  ([W_a;U_a] rows)
    float* xp1   = WU_B  + 131072;        // 8388608 [64][128][1024] t-major
    float* WU    = xp1;                   // alias: 4194304 ([B*T][512])
    float* ctxb  = xp1   + 4194304;       // alias: 2097152

    float* logits = out;                  // [8192][128]
    float* hlast  = out + BB * TT * VV;   // [128][256]

    // 1) pack recurrent weights; fold b_hh(r,z) into xp biases
    pack_whh_f16<<<768, 256, 0, stream>>>(w_hh0, wT0);
    pack_whh_f16<<<768, 256, 0, stream>>>(w_hh1, wT1);
    prep_bias<<<3, 256, 0, stream>>>(b_ih0, b_hh0, bias0);
    prep_bias<<<3, 256, 0, stream>>>(b_ih1, b_hh1, bias1);
    hipMemcpyAsync(WU_B, W_a, HH * HH * sizeof(float),
                   hipMemcpyDeviceToDevice, stream);
    hipMemcpyAsync(WU_B + HH * HH, U_a, HH * HH * sizeof(float),
                   hipMemcpyDeviceToDevice, stream);

    // 2) P0 = embed @ w_ih0.T + bias0  (perm 1: gate-interleaved padded)
    gemm_bt<<<dim3(G3 / 64, VV / 64), 256, 0, stream>>>(
        embed, HH, HH, nullptr, 0, 0, w_ih0, HH, bias0, P0, 0, VV, G3, 1);

    // 3) GRU layer 0 (xp gathered from P0 by token id)
    gru_mfma<<<BB / 16, 512, 0, stream>>>(wT0, b_hh0, P0, x, h1, nullptr, 0);

    // 4) xp1 = h1 @ w_ih1.T + bias1  (perm 2: t-major + gate-interleaved)
    gemm_bt<<<dim3(G3 / 64, BB * TT / 64), 256, 0, stream>>>(
        h1, HH, HH, nullptr, 0, 0, w_ih1, HH, bias1, xp1, 0, BB * TT, G3, 2);

    // 5) GRU layer 1 -> enc, h_last
    gru_mfma<<<BB / 16, 512, 0, stream>>>(wT1, b_hh1, xp1, nullptr, enc, hlast, 1);

    // 6) WU = enc @ [W_a;U_a].T   (8192 x 512, K=256) — merged Wae/Uah
    gemm_bt<<<dim3(512 / 64, BB * TT / 64), 256, 0, stream>>>(
        enc, HH, HH, nullptr, 0, 0, WU_B, HH, nullptr, WU, 512, BB * TT, 512, 0);

    // 7) attention: energy -> softmax -> ctx
    attn_kernel<<<dim3(TT, BB), 256, 0, stream>>>(WU, enc, v_a, ctxb);

    // 8) logits = [enc | ctx] @ fc_W.T + fc_b  (split-A GEMM, K=256+256)
    gemm_bt<<<dim3(VV / 64, BB * TT / 64), 256, 0, stream>>>(
        enc, HH, HH, ctxb, HH, HH, fc_W, 2 * HH, fc_b, logits, VV, BB * TT, VV, 0);
}

// Round 6
// 723.854 us; speedup vs baseline: 1.3609x; 1.3609x over previous
//
#include <hip/hip_runtime.h>
#include <math.h>

// Problem dims (AttentionRNN): B=128, T=64, H=256, V=128
#define BB 128
#define TT 64
#define HH 256
#define G3 768   // 3*H
#define VV 128

typedef _Float16 half8 __attribute__((ext_vector_type(8)));
typedef float f32x4 __attribute__((ext_vector_type(4)));

// ---------------------------------------------------------------------------
// Pack w_hh [768][256] f32 -> f16 MFMA B-fragments, in the exact per-lane
// order gru_mfma consumes: [wave 8][tile 6][ktile 8][lane 64][elem 8].
// Fragment def (v_mfma_f32_16x16x32_f16 B): col = lane&15, k = (lane>>4)*8+e.
// Tile tau: gate g = tau/2, sub s = tau&1 -> ncol = g*256 + wave*32 + s*16.
// ---------------------------------------------------------------------------
__global__ __launch_bounds__(256) void pack_whh_f16(const float* __restrict__ w,
                                                    _Float16* __restrict__ out) {
    int d = blockIdx.x * 256 + threadIdx.x;   // 196608 total
    int e   = d & 7;
    int l   = (d >> 3) & 63;
    int kap = (d >> 9) & 7;
    int wt  = d >> 12;                        // wave*6 + tau
    int wv  = wt / 6, tau = wt % 6;
    int ncol = (tau >> 1) * 256 + wv * 32 + (tau & 1) * 16 + (l & 15);
    int k    = kap * 32 + (l >> 4) * 8 + e;
    out[d] = (_Float16)w[ncol * HH + k];
}

// Folded bias: out[j] = b_ih[j] + (j<512 ? b_hh[j] : 0).  (r,z parts of b_hh
// ride along in xp; the n part stays separate since it's scaled by r.)
__global__ __launch_bounds__(256) void prep_bias(const float* __restrict__ b_ih,
                                                 const float* __restrict__ b_hh,
                                                 float* __restrict__ outb) {
    int j = blockIdx.x * 256 + threadIdx.x;   // 768
    outb[j] = b_ih[j] + (j < 2 * HH ? b_hh[j] : 0.f);
}

// ---------------------------------------------------------------------------
// Generic f32 GEMM: C[M,N] = A[M,K1+K2] @ B[N,K1+K2]^T + bias.
// permmode 0: normal row-major C [M][ldc], float4 stores.
// permmode 1 (N must be 768): xp layout, C[r][c*4+g] width 1024 (j = g*256+c).
// permmode 2: same + t-major row permute r=(b*64+t) -> orow = t*128+b.
// ---------------------------------------------------------------------------
__global__ __launch_bounds__(256) void gemm_bt(
    const float* __restrict__ A1, int lda1, int K1,
    const float* __restrict__ A2, int lda2, int K2,
    const float* __restrict__ Bw, int ldb,
    const float* __restrict__ bias,
    float* __restrict__ C, int ldc, int M, int N, int permmode)
{
    __shared__ alignas(16) float As[16][68];
    __shared__ alignas(16) float Bs[16][68];
    const int tid = threadIdx.x;
    const int lc = tid & 15, lr = tid >> 4;
    const int ty = tid >> 4, tx = tid & 15;
    const int row0 = blockIdx.y * 64, col0 = blockIdx.x * 64;
    float acc[4][4] = {};
    const int KT = K1 + K2;

    for (int k0 = 0; k0 < KT; k0 += 16) {
        const float* Ap; int lda, kk0;
        if (k0 < K1) { Ap = A1; lda = lda1; kk0 = k0; }
        else         { Ap = A2; lda = lda2; kk0 = k0 - K1; }
#pragma unroll
        for (int r = 0; r < 4; ++r) {
            As[lc][lr + 16 * r] = Ap[(row0 + lr + 16 * r) * lda + kk0 + lc];
            Bs[lc][lr + 16 * r] = Bw[(col0 + lr + 16 * r) * ldb + k0 + lc];
        }
        __syncthreads();
#pragma unroll
        for (int kk = 0; kk < 16; ++kk) {
            const float4 a4 = *(const float4*)&As[kk][ty * 4];
            const float4 b4 = *(const float4*)&Bs[kk][tx * 4];
            const float av[4] = {a4.x, a4.y, a4.z, a4.w};
            const float bv[4] = {b4.x, b4.y, b4.z, b4.w};
#pragma unroll
            for (int i = 0; i < 4; ++i)
#pragma unroll
                for (int j = 0; j < 4; ++j)
                    acc[i][j] += av[i] * bv[j];
        }
        __syncthreads();
    }

    float bv[4];
#pragma unroll
    for (int j = 0; j < 4; ++j)
        bv[j] = bias ? bias[col0 + tx * 4 + j] : 0.f;
#pragma unroll
    for (int i = 0; i < 4; ++i) {
        const int r = row0 + ty * 4 + i;
        if (permmode == 0) {
            float4 o;
            o.x = acc[i][0] + bv[0];
            o.y = acc[i][1] + bv[1];
            o.z = acc[i][2] + bv[2];
            o.w = acc[i][3] + bv[3];
            *(float4*)&C[r * ldc + col0 + tx * 4] = o;
        } else {
            const int orow = (permmode == 2) ? ((r & 63) * BB + (r >> 6)) : r;
#pragma unroll
            for (int jj = 0; jj < 4; ++jj) {
                const int j = col0 + tx * 4 + jj;
                const int g = j >> 8, c = j & 255;
                C[orow * 1024 + c * 4 + g] = acc[i][jj] + bv[jj];
            }
        }
    }
}

// ---------------------------------------------------------------------------
// MFMA GRU layer, register-resident weights.
// 8 blocks x 16 batch rows, 512 threads (8 waves), 1 block/CU.
// Per step: issue xp(t) loads (latency hides under MFMA wall) -> 8 ds_read
// A-frags -> 48 MFMA -> gates -> write hbuf[cur^1].
// Double-buffered hbuf + RAW barrier (lgkmcnt(0) only, NO vmcnt drain):
// out_seq stores stay in flight across steps; kernel-end drains them.
// Register budget (2 waves/SIMD = 256): W 192 + acc 24 + xq 24 + ~10 temps.
// xsrc layout: [row][1024] with (xr,xz,xn,pad) at c*4 (see gemm_bt perm).
// mode 0: row = token id (P0).  mode 1: row = t*128 + batch (xp1, t-major).
// ---------------------------------------------------------------------------
__global__ __launch_bounds__(512, 2) void gru_mfma(
    const _Float16* __restrict__ wp,  // packed fragments (see pack_whh_f16)
    const float* __restrict__ b_hh,   // [768]; only [512:768) used here
    const float* __restrict__ xsrc,   // padded xp, width 1024
    const int*   __restrict__ xidx,   // token ids (mode0)
    float* __restrict__ out_seq,      // [B*T][256]
    float* __restrict__ hlast,        // [B][256] (mode1 only)
    int mode)
{
    __shared__ alignas(16) _Float16 hbuf[2][16][264];   // double buffer, +8 pad
    __shared__ int tok[16][TT];                          // mode0 token ids
    const int tid = threadIdx.x;
    const int wv = tid >> 6, l = tid & 63;
    const int l15 = l & 15, lhi = l >> 4;
    const int r0 = blockIdx.x * 16;

    for (int i = tid; i < 16 * 264; i += 512) ((_Float16*)hbuf[0])[i] = (_Float16)0.f;
    if (mode == 0) {
        ((int*)tok)[tid]       = xidx[r0 * TT + tid];
        ((int*)tok)[tid + 512] = xidx[r0 * TT + tid + 512];
    }

    // ---- load all 48 weight fragments into registers (once) ----
    half8 W[48];
    const half8* wp8 = (const half8*)wp;
    const int fb = wv * 48 * 64;
#pragma unroll
    for (int f = 0; f < 48; ++f) W[f] = wp8[fb + f * 64 + l];

    const int colbase = wv * 32 + l15;
    const float bhn0 = b_hh[2 * HH + colbase];
    const float bhn1 = b_hh[2 * HH + colbase + 16];
    __syncthreads();   // hbuf[0] zeros + tok visible

    int cur = 0;
    for (int t = 0; t < TT; ++t) {
        // ---- xp(t) loads issued FIRST; consumed after the MFMA phase ----
        float2 xrz[2][4]; float xn[2][4];
#pragma unroll
        for (int s = 0; s < 2; ++s) {
            const int c = colbase + 16 * s;
#pragma unroll
            for (int reg = 0; reg < 4; ++reg) {
                const int rr = lhi * 4 + reg;
                const long row = (mode == 0) ? (long)tok[rr][t]
                                             : (long)t * BB + (r0 + rr);
                const float* p = &xsrc[row * 1024 + c * 4];
                xrz[s][reg] = *(const float2*)p;
                xn[s][reg]  = p[2];
            }
        }

        f32x4 acc[6];
#pragma unroll
        for (int tau = 0; tau < 6; ++tau) acc[tau] = (f32x4)0.f;

#pragma unroll
        for (int kap = 0; kap < 8; ++kap) {
            const half8 a = *(const half8*)&hbuf[cur][l15][kap * 32 + lhi * 8];
#pragma unroll
            for (int tau = 0; tau < 6; ++tau)
                acc[tau] = __builtin_amdgcn_mfma_f32_16x16x32_f16(
                    a, W[tau * 8 + kap], acc[tau], 0, 0, 0);
        }

        // gates: C-layout col = l&15, row = (l>>4)*4 + reg; write hbuf[cur^1]
#pragma unroll
        for (int s = 0; s < 2; ++s) {
            const int col = colbase + s * 16;
            const float bhn = s ? bhn1 : bhn0;
#pragma unroll
            for (int reg = 0; reg < 4; ++reg) {
                const int row = lhi * 4 + reg;
                const float ho = (float)hbuf[cur][row][col];  // h_old (f16)
                const float pr = acc[0 + s][reg] + xrz[s][reg].x;
                const float pz = acc[2 + s][reg] + xrz[s][reg].y;
                const float hn = acc[4 + s][reg] + bhn;
                const float rg = 1.f / (1.f + __expf(-pr));
                const float zg = 1.f / (1.f + __expf(-pz));
                const float npre = xn[s][reg] + rg * hn;
                const float e2 = __expf(2.f * npre);
                const float ng = (e2 - 1.f) / (e2 + 1.f);
                const float hnew = (1.f - zg) * ng + zg * ho;
                hbuf[cur ^ 1][row][col] = (_Float16)hnew;
                out_seq[((r0 + row) * TT + t) * HH + col] = hnew;
            }
        }

        cur ^= 1;
        // RAW barrier: drain LDS ops only; global stores/loads stay in flight.
        asm volatile("s_waitcnt lgkmcnt(0)" ::: "memory");
        __builtin_amdgcn_s_barrier();
        asm volatile("" ::: "memory");
    }

    if (mode == 1) {
#pragma unroll
        for (int s = 0; s < 2; ++s) {
            const int col = colbase + s * 16;
#pragma unroll
            for (int reg = 0; reg < 4; ++reg) {
                const int row = lhi * 4 + reg;
                hlast[(r0 + row) * HH + col] = (float)hbuf[cur][row][col];
            }
        }
    }
}

// ---------------------------------------------------------------------------
// Bahdanau attention, one block per (b,t): energy -> softmax(k) -> ctx.
// WU holds [Wa_e | Ua_h] per row (stride 512).
// ---------------------------------------------------------------------------
__device__ __forceinline__ float tanh_fast(float x) {
    const float e = __expf(2.f * x);
    return (e - 1.f) / (e + 1.f);
}

__global__ __launch_bounds__(256) void attn_kernel(
    const float* __restrict__ WU,    // [B*T][512]: cols 0..255 Wa_e, 256..511 Ua_h
    const float* __restrict__ enc,   // [B*T][256]
    const float* __restrict__ v_a,   // [256]
    float* __restrict__ ctx)         // [B*T][256]
{
    __shared__ float q[HH], va[HH], sm[TT];
    const int tid = threadIdx.x;
    const int t = blockIdx.x, b = blockIdx.y;

    q[tid]  = WU[(b * TT + t) * 512 + 256 + tid];
    va[tid] = v_a[tid];
    __syncthreads();

    const int w = tid >> 6, lane = tid & 63;
#pragma unroll 4
    for (int i = 0; i < 16; ++i) {
        const int k = w * 16 + i;
        const float* we = WU + (b * TT + k) * 512;
        float s = 0.f;
#pragma unroll
        for (int c = 0; c < 4; ++c) {
            const int h = lane + 64 * c;
            s += va[h] * tanh_fast(we[h] + q[h]);
        }
#pragma unroll
        for (int off = 32; off > 0; off >>= 1) s += __shfl_xor(s, off);
        if (lane == 0) sm[k] = s;
    }
    __syncthreads();

    if (tid < TT) {
        const float e = sm[tid];
        float mx = e;
#pragma unroll
        for (int off = 32; off > 0; off >>= 1) mx = fmaxf(mx, __shfl_xor(mx, off));
        const float p = __expf(e - mx);
        float sum = p;
#pragma unroll
        for (int off = 32; off > 0; off >>= 1) sum += __shfl_xor(sum, off);
        sm[tid] = p / sum;
    }
    __syncthreads();

    float c = 0.f;
    for (int k = 0; k < TT; ++k)
        c += sm[k] * enc[(b * TT + k) * HH + tid];
    ctx[(b * TT + t) * HH + tid] = c;
}

// ---------------------------------------------------------------------------
extern "C" void kernel_launch(void* const* d_in, const int* in_sizes, int n_in,
                              void* d_out, int out_size, void* d_ws, size_t ws_size,
                              hipStream_t stream) {
    const int*   x     = (const int*)  d_in[0];
    const float* embed = (const float*)d_in[1];
    const float* w_ih0 = (const float*)d_in[2];
    const float* w_hh0 = (const float*)d_in[3];
    const float* b_ih0 = (const float*)d_in[4];
    const float* b_hh0 = (const float*)d_in[5];
    const float* w_ih1 = (const float*)d_in[6];
    const float* w_hh1 = (const float*)d_in[7];
    const float* b_ih1 = (const float*)d_in[8];
    const float* b_hh1 = (const float*)d_in[9];
    const float* W_a   = (const float*)d_in[10];
    const float* U_a   = (const float*)d_in[11];
    const float* v_a   = (const float*)d_in[12];
    const float* fc_W  = (const float*)d_in[13];
    const float* fc_b  = (const float*)d_in[14];
    float* out = (float*)d_out;

    // workspace layout (float words); WU/ctx alias dead xp1
    float* ws = (float*)d_ws;
    _Float16* wT0 = (_Float16*)ws;        // 196608 f16 = 98304 f
    _Float16* wT1 = wT0 + 196608;         // 196608 f16
    float* bias0 = ws    + 196608;        // 768
    float* bias1 = bias0 + 768;           // 768
    float* P0    = bias1 + 768;           // 131072  [128][1024] padded xp
    float* h1    = P0    + 131072;        // 2097152
    float* enc   = h1    + 2097152;       // 2097152
    float* WU_B  = enc   + 2097152;       // 131072  ([W_a;U_a] rows)
    float* xp1   = WU_B  + 131072;        // 8388608 [64][128][1024] t-major
    float* WU    = xp1;                   // alias: 4194304 ([B*T][512])
    float* ctxb  = xp1   + 4194304;       // alias: 2097152

    float* logits = out;                  // [8192][128]
    float* hlast  = out + BB * TT * VV;   // [128][256]

    // 1) pack recurrent weights; fold b_hh(r,z) into xp biases
    pack_whh_f16<<<768, 256, 0, stream>>>(w_hh0, wT0);
    pack_whh_f16<<<768, 256, 0, stream>>>(w_hh1, wT1);
    prep_bias<<<3, 256, 0, stream>>>(b_ih0, b_hh0, bias0);
    prep_bias<<<3, 256, 0, stream>>>(b_ih1, b_hh1, bias1);
    hipMemcpyAsync(WU_B, W_a, HH * HH * sizeof(float),
                   hipMemcpyDeviceToDevice, stream);
    hipMemcpyAsync(WU_B + HH * HH, U_a, HH * HH * sizeof(float),
                   hipMemcpyDeviceToDevice, stream);

    // 2) P0 = embed @ w_ih0.T + bias0  (perm 1: gate-interleaved padded)
    gemm_bt<<<dim3(G3 / 64, VV / 64), 256, 0, stream>>>(
        embed, HH, HH, nullptr, 0, 0, w_ih0, HH, bias0, P0, 0, VV, G3, 1);

    // 3) GRU layer 0 (xp gathered from P0 by token id)
    gru_mfma<<<BB / 16, 512, 0, stream>>>(wT0, b_hh0, P0, x, h1, nullptr, 0);

    // 4) xp1 = h1 @ w_ih1.T + bias1  (perm 2: t-major + gate-interleaved)
    gemm_bt<<<dim3(G3 / 64, BB * TT / 64), 256, 0, stream>>>(
        h1, HH, HH, nullptr, 0, 0, w_ih1, HH, bias1, xp1, 0, BB * TT, G3, 2);

    // 5) GRU layer 1 -> enc, h_last
    gru_mfma<<<BB / 16, 512, 0, stream>>>(wT1, b_hh1, xp1, nullptr, enc, hlast, 1);

    // 6) WU = enc @ [W_a;U_a].T   (8192 x 512, K=256) — merged Wae/Uah
    gemm_bt<<<dim3(512 / 64, BB * TT / 64), 256, 0, stream>>>(
        enc, HH, HH, nullptr, 0, 0, WU_B, HH, nullptr, WU, 512, BB * TT, 512, 0);

    // 7) attention: energy -> softmax -> ctx
    attn_kernel<<<dim3(TT, BB), 256, 0, stream>>>(WU, enc, v_a, ctxb);

    // 8) logits = [enc | ctx] @ fc_W.T + fc_b  (split-A GEMM, K=256+256)
    gemm_bt<<<dim3(VV / 64, BB * TT / 64), 256, 0, stream>>>(
        enc, HH, HH, ctxb, HH, HH, fc_W, 2 * HH, fc_b, logits, VV, BB * TT, VV, 0);
}